// Round 11
// baseline (275.108 us; speedup 1.0000x reference)
//
#include <hip/hip_runtime.h>
#include <stdint.h>

// SNN forward with STP/STDP, delays {1,2,3,5}, B=8 T=64 NI=256 N=512 NO=32 D=4.
// ROUND-11: party-count probe, r10's LDS-aliasing bug FIXED.
// 128 blocks = 8 batches x 16 o-chunks (32 o's) -- halves the per-step exchange
// fan-in (16 parties/batch, was 32) while keeping the verified r4 step
// structure: TPB=512 (2 waves/SIMD sweet spot), two lgkmcnt-only barriers,
// prefetch-at-top, LDS-staged records, publish-early, delay-1 staged last.
// 16 e-groups x 32 synapses/lane; acc+STDP FUSED in one loop (acc uses OLD
// ws[i] then updates it -- reference order per synapse; no v[32] staging array).
// r10 BUG: prologue win tile needs NI*OPB = 32 KB but aliased 16.5 KB sxq ->
// overflow corrupted inp_s. FIX: two 128-channel half-tiles (16 KB each, fits
// sxq), per-thread inp rows accumulated in registers (static a[4]), barrier
// between read phase and next-half overwrite.
// Cross-block recurrence: ONE packed 8B record per (t,b,n) = {syn_p, xbar|spike},
// agent-scope relaxed store; "unwritten" = RUN-PARITY TAG in syn_p's sign bit
// (syn_p >= 0 always). Delay-1 plane agent-loaded; delay>=2 plain-loaded
// (write-once => stale == wrong parity -> agent poll fallback). Workspace
// re-poisoned every run => init always runs (parity-fill + done[] barrier).
// Readout fused: per-step 32-bit spike ballot -> partial h2 -> f32 atomics ->
// batch-last block scans. Single dispatch, no memsets.
// PRE-COMMIT: snn_main >= 150us => party count is not the lever; revert to r4
// and declare the synchronization-latency floor.

#define B  8
#define T  64
#define NI 256
#define NN 512
#define NO 32
#define DD 4

#define NBLK 128
#define TPB  512
#define OPB  32          // o's per block
#define EGR  16          // e-groups (tid>>5)
#define SPL  32          // synapses per lane (e = e_grp + 16*i)
#define EPAD 516         // padded per-d LDS plane stride (float2 elems)

#define REC_ELEMS (T*B*NN)   // packed 8B records
#define MAGIC  0x534E4E31u

// ctrl[] layout (u32): [0..7]=cnt per batch, [8]=gcnt, [9]=runpar, [10]=header,
//                      [16..143]=done[] per-block init tags
#define C_CNT   0
#define C_GCNT  8
#define C_PAR   9
#define C_HDR   10
#define C_DONE  16

__device__ __forceinline__ unsigned long long rec_load(const unsigned long long* p) {
    return __hip_atomic_load(p, __ATOMIC_RELAXED, __HIP_MEMORY_SCOPE_AGENT);
}
__device__ __forceinline__ unsigned long long rec_load_plain(const unsigned long long* p) {
    return *p;   // L1/L2-cacheable; write-once data => stale == wrong parity
}
__device__ __forceinline__ void rec_store(unsigned long long* p, unsigned long long v) {
    __hip_atomic_store(p, v, __ATOMIC_RELAXED, __HIP_MEMORY_SCOPE_AGENT);
}
__device__ __forceinline__ unsigned ctrl_ld(const unsigned* p) {
    return __hip_atomic_load(p, __ATOMIC_RELAXED, __HIP_MEMORY_SCOPE_AGENT);
}
__device__ __forceinline__ void ctrl_st(unsigned* p, unsigned v) {
    __hip_atomic_store(p, v, __ATOMIC_RELAXED, __HIP_MEMORY_SCOPE_AGENT);
}
__device__ __forceinline__ bool unwritten(unsigned long long v, unsigned runpar) {
    return ((unsigned)v >> 31) != runpar;   // lo sign bit = run parity tag
}
__device__ __forceinline__ unsigned long long poll_written(
        const unsigned long long* src, unsigned long long v, unsigned runpar) {
    int guard = 0;
    while (unwritten(v, runpar)) {
        if (guard >= 2) __builtin_amdgcn_s_sleep(1);   // fast-retry first
        v = rec_load(src);                             // authoritative (agent)
        if (++guard > (1 << 18)) break;                // fail loud, not hung
    }
    return v;
}

// Raw barrier: drain LDS only (NOT vmcnt) -- prefetch loads / publish store
// stay in flight across the barrier.
#define BAR_LDS() do {                                      \
    asm volatile("s_waitcnt lgkmcnt(0)" ::: "memory");      \
    __builtin_amdgcn_s_barrier();                           \
    asm volatile("" ::: "memory");                          \
} while (0)

__global__ __launch_bounds__(TPB, 2)
void snn_main(const float* __restrict__ inputs,
              const float* __restrict__ w,
              const float* __restrict__ w_in,
              const float* __restrict__ w_out,
              const float* __restrict__ dmap,
              const int*   __restrict__ delays,
              const float* __restrict__ w_signs,
              const float* __restrict__ p,
              const float* __restrict__ A_p,
              const float* __restrict__ A_d,
              unsigned long long* __restrict__ rec,
              float* __restrict__ h2buf,
              unsigned* __restrict__ ctrl,
              float* __restrict__ out)
{
    // LDS: sxq[d][e] padded planes = {syn_p, xbar|spikebit}. 16512 B.
    // acc read: within a half-wave e is uniform, d in {0..3} -> bank
    // (8d+2e)%32: 4 distinct banks, broadcast within each d-group.
    __shared__ float2 sxq[DD*EPAD];
    __shared__ float  inp_s[T*OPB];        // per-block input-current slice (8 KB)
    __shared__ float  red[8*OPB];          // 8 wave partials for the e-reduction
    __shared__ unsigned int spikebits_s[T];// this block's 32 neurons' spikes per step
    __shared__ float  wout_s[OPB*NO];      // w_out rows of this block's neurons (4 KB)
    __shared__ float  h2_s[T*NO];          // last-block scan staging (8 KB)
    __shared__ int    last_s;

    const int tid     = threadIdx.x;
    const int bid     = blockIdx.x;
    const int b       = bid & 7;           // round-robin => batch b lives on XCD b
    const int chunk   = bid >> 3;          // 0..15
    const int o_base  = chunk * OPB;
    const int o_local = tid & 31;
    const int e_grp   = tid >> 5;          // 0..15
    const int o       = o_base + o_local;

    // ---------------- init (runs every launch: ws is re-poisoned) -----------
    unsigned runpar;
    if (ctrl_ld(ctrl + C_HDR) != MAGIC) {
        // fill own rec slice: lo-sign=1 => "unwritten for run parity 0"
        {
            unsigned long long* base = rec + (size_t)bid * (REC_ELEMS / NBLK);
            #pragma unroll
            for (int i = 0; i < REC_ELEMS / NBLK / TPB; ++i)
                rec_store(base + i*TPB + tid, 0x0000000080000000ull);
        }
        // zero own h2 slice
        {
            unsigned* hb = (unsigned*)h2buf + (size_t)bid * ((B*T*NO) / NBLK);
            if (tid < (B*T*NO) / NBLK) ctrl_st(hb + tid, 0u);
        }
        if (bid == 0 && tid < 10) ctrl_st(ctrl + tid, 0u);  // cnt[8], gcnt, par
        __syncthreads();                    // drains vmcnt(0): all stores acked
        if (tid == 0) ctrl_st(ctrl + C_DONE + bid, MAGIC);
        // single grid arrival barrier: thread j watches done[j]
        if (tid < NBLK) {
            int guard = 0;
            while (ctrl_ld(ctrl + C_DONE + tid) != MAGIC) {
                __builtin_amdgcn_s_sleep(2);
                if (++guard > (1 << 20)) break;
            }
        }
        __syncthreads();
        runpar = 0u;
    } else {
        runpar = ctrl_ld(ctrl + C_PAR);     // ws persisted: fast path
    }

    // ---- publish slot 0 (zero record, parity-tagged) FIRST ----
    if (tid < OPB) {
        rec_store(rec + (size_t)(0*B + b)*NN + o_base + tid,
                  (unsigned long long)(runpar << 31));
    }
    if (tid == 0) spikebits_s[0] = 0u;

    // ---------------- per-lane synapse constants (registers) -----------------
    float wv[SPL], ap[SPL], ad[SPL], ws[SPL];
    int   laddr[SPL];                 // precomputed LDS byte offset of (d,e) slot
    #pragma unroll
    for (int i = 0; i < SPL; ++i) {
        const int e = e_grp + EGR*i;
        wv[i] = w_signs[e] * fabsf(w[e*NN + o]);
        ap[i] = A_p[e*NN + o];
        ad[i] = A_d[e*NN + o];
        int d = 0;                    // argmax_d of one-hot dmap
        if (dmap[1*NN*NN + e*NN + o] != 0.0f) d = 1;
        if (dmap[2*NN*NN + e*NN + o] != 0.0f) d = 2;
        if (dmap[3*NN*NN + e*NN + o] != 0.0f) d = 3;
        ws[i]    = 1.0f;
        laddr[i] = (d*EPAD + e) * 8;
    }
    int del[DD];
    #pragma unroll
    for (int d = 0; d < DD; ++d) del[d] = delays[d];

    // ---------------- prologue: inp[b,t,o] slice = inputs @ w_in -------------
    // Two 128-channel half-tiles (128*32 floats = 16 KB each <= 16512 B sxq);
    // per-thread rows accumulate in registers (static a[4]); barrier separates
    // the read phase from the next half's overwrite.
    {
        float* win = (float*)sxq;     // 4096 floats per half, prologue-only
        float a[T/EGR];
        #pragma unroll
        for (int j = 0; j < T/EGR; ++j) a[j] = 0.f;
        #pragma unroll
        for (int half = 0; half < 2; ++half) {
            const int c0 = half * (NI/2);
            #pragma unroll
            for (int q = 0; q < (NI/2)*OPB/TPB; ++q) {
                const int k = q*TPB + tid;
                const int c = k >> 5, oo = k & 31;
                win[c*OPB + oo] = w_in[(c0 + c)*NN + o_base + oo];
            }
            __syncthreads();          // half-tile staged
            #pragma unroll
            for (int j = 0; j < T/EGR; ++j) {     // 4 rows per thread
                const int tj = e_grp*(T/EGR) + j;
                const float* inrow = inputs + (size_t)(b*T + tj)*NI + c0;
                float s = 0.f;
                for (int c = 0; c < NI/2; ++c) s += inrow[c] * win[c*OPB + o_local];
                a[j] += s;
            }
            __syncthreads();          // all win reads done before overwrite
        }
        #pragma unroll
        for (int j = 0; j < T/EGR; ++j)
            inp_s[(e_grp*(T/EGR) + j)*OPB + o_local] = a[j];
        __syncthreads();
    }

    // zero-fill sxq for step 0 (all delays > 0 => all gathered slots are zero)
    #pragma unroll
    for (int d = 0; d < DD; ++d)
        sxq[d*EPAD + tid] = make_float2(0.f, 0.f);
    __syncthreads();

    // neuron state, replicated across the 16 e_grp threads sharing an o
    float mem = 0.f, w_p = 0.f, x_bar = 0.f, u_pot = 0.f, u_dep = 0.f;
    const float p_o  = p[o];
    const float pd_o = (p_o < 0.f) ? 1.f : 0.f;

    unsigned long long pf[DD];        // prefetched records for next step (ALL d)
    const int stage_ord[DD] = {1, 2, 3, 0};   // delay-1 plane (del[0]) staged LAST

    for (int t = 0; t < T; ++t) {
        // ---- prefetch ALL delay planes for step t+1 (in flight across barriers).
        // delay-1 = agent (first-touch); delay>=2 = plain (L1/L2 re-read hit) ----
        if (t + 1 < T) {
            #pragma unroll
            for (int d = 0; d < DD; ++d) {
                if (t + 1 >= del[d]) {
                    const int s = (t + 1 - del[d]) & 63;
                    const unsigned long long* src = rec + (size_t)(s*B + b)*NN + tid;
                    pf[d] = (del[d] == 1) ? rec_load(src) : rec_load_plain(src);
                }
            }
        }

        // ---- FUSED acc+STDP loop: 32 synapses/lane, no staging array.
        // acc uses OLD ws[i] before the update (reference order per synapse);
        // gates (spike/pg/udr) are pre-update state computed at loop top. ----
        const float spike = (mem > 1.0f) ? 1.0f : 0.0f;
        const float pg  = spike * fmaxf(u_pot, 0.f);
        const float udr = fmaxf(u_dep, 0.f);
        float acc = 0.f;
        #pragma unroll
        for (int i = 0; i < SPL; ++i) {
            const float2 v = *(const float2*)((const char*)sxq + laddr[i]);
            acc = fmaf(v.x, wv[i]*ws[i], acc);         // syn uses OLD w_stdp
            const unsigned int xu = __float_as_uint(v.y);
            const float dep = ((int)xu < 0) ? ad[i]*udr : 0.f;  // X in sign bit
            const float pot = (ap[i]*pg) * fabsf(v.y);
            ws[i] = fminf(fmaxf(ws[i] + pot - dep, 0.f), 2.f);
        }
        // reduce over e: lanes l and l^32 share o_local -> one xor-shuffle,
        // then 8 wave partials (one per wave, 2 e_grps pre-combined).
        const float a2 = acc + __shfl_xor(acc, 32);
        if ((tid & 63) < 32) red[(tid >> 6)*32 + o_local] = a2;
        BAR_LDS();         // B1: red visible block-wide; vmem stays in flight
        float syn = 0.f;
        #pragma unroll
        for (int k = 0; k < 8; ++k) syn += red[k*32 + o_local];

        // ---- state updates (reference order; u's use pre-update mem) ----
        const float wp_new = 0.85f*w_p + spike * p_o * (1.f + pd_o*w_p);
        const float xb_new = 0.95f*x_bar + 0.05f*spike;
        u_pot = 0.95f*u_pot + 0.05f*mem;
        u_dep = 0.95f*u_dep + 0.05f*mem;
        mem   = 0.9f*mem + inp_s[t*OPB + o_local] + syn - spike;
        w_p   = wp_new;
        x_bar = xb_new;

        // ---- publish record for step t+1 EARLY (before staging polls) ----
        if (t + 1 < T && tid < OPB) {
            const float spike1 = (mem > 1.0f) ? 1.0f : 0.0f;
            const float sp = spike1 * (1.f + w_p);     // >= 0: sign bit free
            const unsigned int xu = __float_as_uint(x_bar) | (spike1 != 0.f ? 0x80000000u : 0u);
            const unsigned int lo = __float_as_uint(sp) | (runpar << 31);
            const unsigned long long pk = ((unsigned long long)xu << 32) | lo;
            rec_store(rec + (size_t)((t+1)*B + b)*NN + o_base + tid, pk);
            const unsigned long long bal = __ballot(spike1 != 0.0f);
            if (tid == 0) spikebits_s[t+1] = (unsigned int)bal;   // bits 0..31
        }

        // ---- stage step t+1 into LDS from prefetch; delay-1 plane LAST ----
        if (t + 1 < T) {
            #pragma unroll
            for (int j = 0; j < DD; ++j) {
                const int d = stage_ord[j];
                unsigned long long v0 = (unsigned long long)(runpar << 31);
                if (t + 1 >= del[d]) {
                    const int s = (t + 1 - del[d]) & 63;
                    const unsigned long long* src = rec + (size_t)(s*B + b)*NN + tid;
                    v0 = poll_written(src, pf[d], runpar);
                }
                sxq[d*EPAD + tid] =
                    make_float2(__uint_as_float((unsigned)v0 & 0x7fffffffu),
                                __uint_as_float((unsigned)(v0 >> 32)));
            }
        }
        BAR_LDS();         // B2: sxq staged for t+1; red reads of t done
    }

    // ================= fused readout =================
    // (1) per-block partial h2 over its own 32 neurons, from the LDS spike bitmap
    for (int k = tid; k < OPB*NO; k += TPB)
        wout_s[k] = w_out[(o_base + (k >> 5))*NO + (k & 31)];
    __syncthreads();

    const int g  = tid >> 5;        // 0..15 -> t-sixteenth
    const int oo = tid & 31;        // output index
    #pragma unroll
    for (int j = 0; j < 4; ++j) {
        const int t = g*4 + j;
        const unsigned int bits = spikebits_s[t];
        float a = 0.f;
        #pragma unroll
        for (int i = 0; i < OPB; ++i)
            if (bits & (1u << i)) a += wout_s[i*NO + oo];
        if (a != 0.f) atomicAdd(h2buf + ((size_t)b*T + t)*NO + oo, a);
    }
    __threadfence();                 // make our h2 atomics visible before arrival
    __syncthreads();
    if (tid == 0) last_s = (atomicAdd(ctrl + C_CNT + b, 1u) == (NBLK/B - 1)) ? 1 : 0;
    __syncthreads();

    if (last_s) {
        // (2) last-arriving block of batch b: gather h2, leaky scan
        __threadfence();
        #pragma unroll
        for (int j = 0; j < 4; ++j) {
            const int t = g*4 + j;
            h2_s[t*NO + oo] = __hip_atomic_load(h2buf + ((size_t)b*T + t)*NO + oo,
                                                __ATOMIC_RELAXED, __HIP_MEMORY_SCOPE_AGENT);
        }
        __syncthreads();
        if (tid < NO) {
            float st = 0.f;
            for (int t = 0; t < T; ++t) {
                st = 0.9f*st + h2_s[t*NO + tid];
                out[((size_t)b*T + t)*NO + tid] = st;
            }
        }
    }

    // ---- global arrival: the last block flips run state for the next launch ----
    if (tid == 0) {
        const unsigned gar = __hip_atomic_fetch_add(ctrl + C_GCNT, 1u,
                                                    __ATOMIC_ACQ_REL, __HIP_MEMORY_SCOPE_AGENT);
        if (gar == NBLK - 1) {
            for (int i = 0; i < 8; ++i) ctrl_st(ctrl + C_CNT + i, 0u);
            ctrl_st(ctrl + C_GCNT, 0u);
            ctrl_st(ctrl + C_PAR, runpar ^ 1u);
            ctrl_st(ctrl + C_HDR, MAGIC);
        }
    }
}

extern "C" void kernel_launch(void* const* d_in, const int* in_sizes, int n_in,
                              void* d_out, int out_size, void* d_ws, size_t ws_size,
                              hipStream_t stream)
{
    const float* inputs  = (const float*)d_in[0];
    const float* w       = (const float*)d_in[1];
    const float* w_in    = (const float*)d_in[2];
    const float* w_out   = (const float*)d_in[3];
    const float* dmap    = (const float*)d_in[4];
    const int*   delays  = (const int*)  d_in[5];
    const float* w_signs = (const float*)d_in[6];
    const float* p       = (const float*)d_in[7];
    const float* A_p     = (const float*)d_in[8];
    const float* A_d     = (const float*)d_in[9];

    char* wsb = (char*)d_ws;
    unsigned long long* rec = (unsigned long long*)wsb;            // 2 MB packed records
    float* h2buf = (float*)(wsb + (size_t)REC_ELEMS*8);            // 64 KB
    unsigned* ctrl = (unsigned*)(wsb + (size_t)REC_ELEMS*8 + (size_t)B*T*NO*4);

    // Single dispatch: init (parity fill + one grid tag-barrier) runs in-kernel.
    hipLaunchKernelGGL(snn_main, dim3(NBLK), dim3(TPB), 0, stream,
                       inputs, w, w_in, w_out, dmap, delays, w_signs, p, A_p, A_d,
                       rec, h2buf, ctrl, (float*)d_out);
}

// Round 12
// 222.506 us; speedup vs baseline: 1.2364x; 1.2364x over previous
//
#include <hip/hip_runtime.h>
#include <stdint.h>

// SNN forward with STP/STDP, delays {1,2,3,5}, B=8 T=64 NI=256 N=512 NO=32 D=4.
// Persistent dataflow kernel: 256 blocks = 8 batches x 32 o-chunks (16 o's).
// SESSION-FINAL (round-4 structure; verified twice at ~224us total):
//  * 512 threads/block = 8 waves/CU = 2 waves/SIMD -- measured sweet spot
//    (1/SIMD: 3.3us/step; 2/SIMD: 2.4; 4/SIMD: 2.7). 32 e-groups x 16 syn/lane.
//  * two lgkmcnt-only barriers/step; prefetch at top (full-step latency cover),
//    LDS-staged records (dedup: 4 loads/thread feed 16 consumers each),
//    publish EARLY (decoupled from staging polls), STDP loop covers publish
//    visibility.
//  * Measured-worse alternatives: register pass-through (r7, +131%),
//    polls-before-barrier single-barrier (r5, +19%), dual-store L2 path
//    (r1, +28%), 4 waves/SIMD (r6, +12%), 16 parties/batch (r11, +33%).
// Floor diagnosis: 64 sequential grid-section exchanges (publish -> L3
// visibility -> consume across 32 blocks/batch) x ~2.4us; HBM 2.8%, VALU 29%,
// no spills, conflicts 2-way-free -- latency-bound, not resource-bound.
// Cross-block recurrence: ONE packed 8B record per (t,b,n) = {syn_p, xbar|spike},
// agent-scope relaxed atomic store; "unwritten" = RUN-PARITY TAG in syn_p's
// sign bit (syn_p >= 0 always). Delay-1 plane agent-loaded (first touch);
// delay>=2 planes plain-loaded (L1/L2 re-read hits; write-once => stale ==
// wrong parity -> agent poll fallback). Workspace re-poisoned every run =>
// init always runs: parity-fill own rec slice + one done[]-tag grid barrier.
// Readout fused: per-step 16-bit spike ballot -> partial h2 -> f32 atomics ->
// batch-last block scans. Single dispatch, no memsets.

#define B  8
#define T  64
#define NI 256
#define NN 512
#define NO 32
#define DD 4

#define NBLK 256
#define TPB  512
#define OPB  16          // o's per block
#define EGR  32          // e-groups (tid>>4)
#define SPL  16          // synapses per lane (e = e_grp + 32*i)
#define EPAD 516         // padded per-d LDS plane stride (float2 elems)

#define REC_ELEMS (T*B*NN)   // packed 8B records
#define MAGIC  0x534E4E31u

// ctrl[] layout (u32): [0..7]=cnt per batch, [8]=gcnt, [9]=runpar, [10]=header,
//                      [16..271]=done[] per-block init tags
#define C_CNT   0
#define C_GCNT  8
#define C_PAR   9
#define C_HDR   10
#define C_DONE  16

__device__ __forceinline__ unsigned long long rec_load(const unsigned long long* p) {
    return __hip_atomic_load(p, __ATOMIC_RELAXED, __HIP_MEMORY_SCOPE_AGENT);
}
__device__ __forceinline__ unsigned long long rec_load_plain(const unsigned long long* p) {
    return *p;   // L1/L2-cacheable; write-once data => stale == wrong parity
}
__device__ __forceinline__ void rec_store(unsigned long long* p, unsigned long long v) {
    __hip_atomic_store(p, v, __ATOMIC_RELAXED, __HIP_MEMORY_SCOPE_AGENT);
}
__device__ __forceinline__ unsigned ctrl_ld(const unsigned* p) {
    return __hip_atomic_load(p, __ATOMIC_RELAXED, __HIP_MEMORY_SCOPE_AGENT);
}
__device__ __forceinline__ void ctrl_st(unsigned* p, unsigned v) {
    __hip_atomic_store(p, v, __ATOMIC_RELAXED, __HIP_MEMORY_SCOPE_AGENT);
}
__device__ __forceinline__ bool unwritten(unsigned long long v, unsigned runpar) {
    return ((unsigned)v >> 31) != runpar;   // lo sign bit = run parity tag
}
__device__ __forceinline__ unsigned long long poll_written(
        const unsigned long long* src, unsigned long long v, unsigned runpar) {
    int guard = 0;
    while (unwritten(v, runpar)) {
        if (guard >= 2) __builtin_amdgcn_s_sleep(1);   // fast-retry first
        v = rec_load(src);                             // authoritative (agent)
        if (++guard > (1 << 18)) break;                // fail loud, not hung
    }
    return v;
}

// Raw barrier: drain LDS only (NOT vmcnt) -- prefetch loads / publish store
// stay in flight across the barrier. Compiler still inserts counted vmcnt
// waits before any use of load results.
#define BAR_LDS() do {                                      \
    asm volatile("s_waitcnt lgkmcnt(0)" ::: "memory");      \
    __builtin_amdgcn_s_barrier();                           \
    asm volatile("" ::: "memory");                          \
} while (0)

__global__ __launch_bounds__(TPB, 2)
void snn_main(const float* __restrict__ inputs,
              const float* __restrict__ w,
              const float* __restrict__ w_in,
              const float* __restrict__ w_out,
              const float* __restrict__ dmap,
              const int*   __restrict__ delays,
              const float* __restrict__ w_signs,
              const float* __restrict__ p,
              const float* __restrict__ A_p,
              const float* __restrict__ A_d,
              unsigned long long* __restrict__ rec,
              float* __restrict__ h2buf,
              unsigned* __restrict__ ctrl,
              float* __restrict__ out)
{
    // LDS: sxq[d][e] padded planes = {syn_p, xbar|spikebit}. 16512 B.
    __shared__ float2 sxq[DD*EPAD];
    __shared__ float  inp_s[T*OPB];        // per-block input-current slice
    __shared__ float  red[8*OPB];          // 8 wave partials for the e-reduction
    __shared__ unsigned int spikebits_s[T];// this block's 16 neurons' spikes per step
    __shared__ float  wout16_s[OPB*NO];    // w_out rows of this block's neurons
    __shared__ float  h2_s[T*NO];          // last-block scan staging
    __shared__ int    last_s;

    const int tid     = threadIdx.x;
    const int bid     = blockIdx.x;
    const int b       = bid & 7;           // round-robin => batch b lives on XCD b
    const int chunk   = bid >> 3;
    const int o_base  = chunk * OPB;
    const int o_local = tid & 15;
    const int e_grp   = tid >> 4;          // 0..31
    const int o       = o_base + o_local;

    // ---------------- init (runs every launch: ws is re-poisoned) -----------
    unsigned runpar;
    if (ctrl_ld(ctrl + C_HDR) != MAGIC) {
        // fill own rec slice: lo-sign=1 => "unwritten for run parity 0"
        {
            unsigned long long* base = rec + (size_t)bid * (REC_ELEMS / NBLK);
            #pragma unroll
            for (int i = 0; i < REC_ELEMS / NBLK / TPB; ++i)
                rec_store(base + i*TPB + tid, 0x0000000080000000ull);
        }
        // zero own h2 slice
        {
            unsigned* hb = (unsigned*)h2buf + (size_t)bid * ((B*T*NO) / NBLK);
            if (tid < (B*T*NO) / NBLK) ctrl_st(hb + tid, 0u);
        }
        if (bid == 0 && tid < 10) ctrl_st(ctrl + tid, 0u);  // cnt[8], gcnt, par
        __syncthreads();                    // drains vmcnt(0): all stores acked
        if (tid == 0) ctrl_st(ctrl + C_DONE + bid, MAGIC);
        // single grid arrival barrier: thread j watches done[j]
        if (tid < NBLK) {
            int guard = 0;
            while (ctrl_ld(ctrl + C_DONE + tid) != MAGIC) {
                __builtin_amdgcn_s_sleep(2);
                if (++guard > (1 << 20)) break;
            }
        }
        __syncthreads();
        runpar = 0u;
    } else {
        runpar = ctrl_ld(ctrl + C_PAR);     // ws persisted: fast path
    }

    // ---- publish slot 0 (zero record, parity-tagged) FIRST ----
    if (tid < OPB) {
        rec_store(rec + (size_t)(0*B + b)*NN + o_base + tid,
                  (unsigned long long)(runpar << 31));
    }
    if (tid == 0) spikebits_s[0] = 0u;

    // ---------------- per-lane synapse constants (registers) -----------------
    float wv[SPL], ap[SPL], ad[SPL], ws[SPL];
    int   laddr[SPL];                 // precomputed LDS byte offset of (d,e) slot
    #pragma unroll
    for (int i = 0; i < SPL; ++i) {
        const int e = e_grp + EGR*i;
        wv[i] = w_signs[e] * fabsf(w[e*NN + o]);
        ap[i] = A_p[e*NN + o];
        ad[i] = A_d[e*NN + o];
        int d = 0;                    // argmax_d of one-hot dmap
        if (dmap[1*NN*NN + e*NN + o] != 0.0f) d = 1;
        if (dmap[2*NN*NN + e*NN + o] != 0.0f) d = 2;
        if (dmap[3*NN*NN + e*NN + o] != 0.0f) d = 3;
        ws[i]    = 1.0f;
        laddr[i] = (d*EPAD + e) * 8;
    }
    int del[DD];
    #pragma unroll
    for (int d = 0; d < DD; ++d) del[d] = delays[d];

    // ---------------- prologue: inp[b,t,o] slice = inputs @ w_in -------------
    {
        float* win = (float*)sxq;     // 4096 floats alias, prologue-only
        #pragma unroll
        for (int q = 0; q < NI*OPB/TPB; ++q) {
            const int k = q*TPB + tid;
            const int c = k >> 4, oo = k & 15;
            win[c*OPB + oo] = w_in[c*NN + o_base + oo];
        }
        __syncthreads();
        #pragma unroll
        for (int j = 0; j < T/EGR; ++j) {     // 2 rows per thread
            const int tj = e_grp*(T/EGR) + j;
            const float* inrow = inputs + (size_t)(b*T + tj)*NI;
            float a = 0.f;
            for (int c = 0; c < NI; ++c) a += inrow[c] * win[c*OPB + o_local];
            inp_s[tj*OPB + o_local] = a;
        }
        __syncthreads();
    }

    // zero-fill sxq for step 0 (all delays > 0 => all gathered slots are zero)
    #pragma unroll
    for (int d = 0; d < DD; ++d)
        sxq[d*EPAD + tid] = make_float2(0.f, 0.f);
    __syncthreads();

    // neuron state, replicated across the 32 e_grp threads sharing an o
    float mem = 0.f, w_p = 0.f, x_bar = 0.f, u_pot = 0.f, u_dep = 0.f;
    const float p_o  = p[o];
    const float pd_o = (p_o < 0.f) ? 1.f : 0.f;

    unsigned long long pf[DD];        // prefetched records for next step (ALL d)
    const int stage_ord[DD] = {1, 2, 3, 0};   // delay-1 plane (del[0]) staged LAST

    for (int t = 0; t < T; ++t) {
        // ---- prefetch ALL delay planes for step t+1 (in flight across barriers).
        // delay-1 = agent (first-touch); delay>=2 = plain (L1/L2 re-read hit) ----
        if (t + 1 < T) {
            #pragma unroll
            for (int d = 0; d < DD; ++d) {
                if (t + 1 >= del[d]) {
                    const int s = (t + 1 - del[d]) & 63;
                    const unsigned long long* src = rec + (size_t)(s*B + b)*NN + tid;
                    pf[d] = (del[d] == 1) ? rec_load(src) : rec_load_plain(src);
                }
            }
        }

        // ---- acc-only loop: 16 synapses/lane, keep staged v[] in registers ----
        const float spike = (mem > 1.0f) ? 1.0f : 0.0f;
        const float pg  = spike * fmaxf(u_pot, 0.f);   // STDP gates: pre-update u's
        const float udr = fmaxf(u_dep, 0.f);
        float2 v[SPL];
        float acc = 0.f;
        #pragma unroll
        for (int i = 0; i < SPL; ++i) {
            v[i] = *(const float2*)((const char*)sxq + laddr[i]);
            acc = fmaf(v[i].x, wv[i]*ws[i], acc);      // syn uses OLD w_stdp
        }
        // reduce over e: intra-wave xor-shuffles (4 e_grps/wave), 8 wave partials
        float a2 = acc + __shfl_xor(acc, 16);
        a2 += __shfl_xor(a2, 32);
        if ((tid & 63) < 16) red[(tid >> 6)*16 + o_local] = a2;
        BAR_LDS();         // B1: red visible block-wide; vmem stays in flight
        float syn = 0.f;
        #pragma unroll
        for (int k = 0; k < 8; ++k) syn += red[k*16 + o_local];

        // ---- state updates (reference order; u's use pre-update mem) ----
        const float wp_new = 0.85f*w_p + spike * p_o * (1.f + pd_o*w_p);
        const float xb_new = 0.95f*x_bar + 0.05f*spike;
        u_pot = 0.95f*u_pot + 0.05f*mem;
        u_dep = 0.95f*u_dep + 0.05f*mem;
        mem   = 0.9f*mem + inp_s[t*OPB + o_local] + syn - spike;
        w_p   = wp_new;
        x_bar = xb_new;

        // ---- publish record for step t+1 EARLY (before STDP loop) ----
        if (t + 1 < T && tid < OPB) {
            const float spike1 = (mem > 1.0f) ? 1.0f : 0.0f;
            const float sp = spike1 * (1.f + w_p);     // >= 0: sign bit free
            const unsigned int xu = __float_as_uint(x_bar) | (spike1 != 0.f ? 0x80000000u : 0u);
            const unsigned int lo = __float_as_uint(sp) | (runpar << 31);
            const unsigned long long pk = ((unsigned long long)xu << 32) | lo;
            rec_store(rec + (size_t)((t+1)*B + b)*NN + o_base + tid, pk);
            const unsigned long long bal = __ballot(spike1 != 0.0f);
            if (tid == 0) spikebits_s[t+1] = (unsigned int)bal;
        }

        // ---- STDP ws-update (covers publish visibility; uses pre-update gates) --
        #pragma unroll
        for (int i = 0; i < SPL; ++i) {
            const unsigned int xu = __float_as_uint(v[i].y);
            const float dep = ((int)xu < 0) ? ad[i]*udr : 0.f;  // X in sign bit
            const float pot = (ap[i]*pg) * fabsf(v[i].y);
            ws[i] = fminf(fmaxf(ws[i] + pot - dep, 0.f), 2.f);
        }

        // ---- stage step t+1 into LDS from prefetch; delay-1 plane LAST ----
        if (t + 1 < T) {
            #pragma unroll
            for (int j = 0; j < DD; ++j) {
                const int d = stage_ord[j];
                unsigned long long v0 = (unsigned long long)(runpar << 31);
                if (t + 1 >= del[d]) {
                    const int s = (t + 1 - del[d]) & 63;
                    const unsigned long long* src = rec + (size_t)(s*B + b)*NN + tid;
                    v0 = poll_written(src, pf[d], runpar);
                }
                sxq[d*EPAD + tid] =
                    make_float2(__uint_as_float((unsigned)v0 & 0x7fffffffu),
                                __uint_as_float((unsigned)(v0 >> 32)));
            }
        }
        BAR_LDS();         // B2: sxq staged for t+1; red reads of t done
    }

    // ================= fused readout =================
    // (1) per-block partial h2 over its own 16 neurons, from the LDS spike bitmap
    if (tid < OPB*NO) wout16_s[tid] = w_out[(o_base + (tid >> 5))*NO + (tid & 31)];
    __syncthreads();

    const int g  = tid >> 5;        // 0..15 -> t-sixteenth
    const int oo = tid & 31;        // output index
    #pragma unroll
    for (int j = 0; j < 4; ++j) {
        const int t = g*4 + j;
        const unsigned int bits = spikebits_s[t];
        float a = 0.f;
        #pragma unroll
        for (int i = 0; i < OPB; ++i)
            if (bits & (1u << i)) a += wout16_s[i*NO + oo];
        if (a != 0.f) atomicAdd(h2buf + ((size_t)b*T + t)*NO + oo, a);
    }
    __threadfence();                 // make our h2 atomics visible before arrival
    __syncthreads();
    if (tid == 0) last_s = (atomicAdd(ctrl + C_CNT + b, 1u) == 31u) ? 1 : 0;
    __syncthreads();

    if (last_s) {
        // (2) last-arriving block of batch b: gather h2, leaky scan
        __threadfence();
        #pragma unroll
        for (int j = 0; j < 4; ++j) {
            const int t = g*4 + j;
            h2_s[t*NO + oo] = __hip_atomic_load(h2buf + ((size_t)b*T + t)*NO + oo,
                                                __ATOMIC_RELAXED, __HIP_MEMORY_SCOPE_AGENT);
        }
        __syncthreads();
        if (tid < NO) {
            float st = 0.f;
            for (int t = 0; t < T; ++t) {
                st = 0.9f*st + h2_s[t*NO + tid];
                out[((size_t)b*T + t)*NO + tid] = st;
            }
        }
    }

    // ---- global arrival: the 256th block flips run state for the next launch ----
    if (tid == 0) {
        const unsigned gar = __hip_atomic_fetch_add(ctrl + C_GCNT, 1u,
                                                    __ATOMIC_ACQ_REL, __HIP_MEMORY_SCOPE_AGENT);
        if (gar == NBLK - 1) {
            for (int i = 0; i < 8; ++i) ctrl_st(ctrl + C_CNT + i, 0u);
            ctrl_st(ctrl + C_GCNT, 0u);
            ctrl_st(ctrl + C_PAR, runpar ^ 1u);
            ctrl_st(ctrl + C_HDR, MAGIC);
        }
    }
}

extern "C" void kernel_launch(void* const* d_in, const int* in_sizes, int n_in,
                              void* d_out, int out_size, void* d_ws, size_t ws_size,
                              hipStream_t stream)
{
    const float* inputs  = (const float*)d_in[0];
    const float* w       = (const float*)d_in[1];
    const float* w_in    = (const float*)d_in[2];
    const float* w_out   = (const float*)d_in[3];
    const float* dmap    = (const float*)d_in[4];
    const int*   delays  = (const int*)  d_in[5];
    const float* w_signs = (const float*)d_in[6];
    const float* p       = (const float*)d_in[7];
    const float* A_p     = (const float*)d_in[8];
    const float* A_d     = (const float*)d_in[9];

    char* wsb = (char*)d_ws;
    unsigned long long* rec = (unsigned long long*)wsb;            // 2 MB packed records
    float* h2buf = (float*)(wsb + (size_t)REC_ELEMS*8);            // 64 KB
    unsigned* ctrl = (unsigned*)(wsb + (size_t)REC_ELEMS*8 + (size_t)B*T*NO*4);

    // Single dispatch: init (parity fill + one grid tag-barrier) runs in-kernel.
    hipLaunchKernelGGL(snn_main, dim3(NBLK), dim3(TPB), 0, stream,
                       inputs, w, w_in, w_out, dmap, delays, w_signs, p, A_p, A_d,
                       rec, h2buf, ctrl, (float*)d_out);
}